// Round 11
// baseline (269.533 us; speedup 1.0000x reference)
//
#include <hip/hip_runtime.h>
#include <math.h>

#define Bn 2
#define DM 192
#define DI 384
#define DS 16
#define HH 64
#define WW 64
#define HW 4096
#define ND 4

typedef __attribute__((ext_vector_type(2))) float v2f;
union Q4 { float4 f4; v2f v2[2]; };

__device__ __forceinline__ float fastrcp(float x) { return __builtin_amdgcn_rcpf(x); }
__device__ __forceinline__ float fsig(float x) {
    return fastrcp(1.0f + __expf(-x));
}

// ---------------- K1: in_proj (1x1) + SiLU ----------------
// grid (16, 24, 2), block 256. Packed v_pk_fma_f32 over channel pairs.
__global__ __launch_bounds__(256, 3) void k_inproj(const float* __restrict__ x,
                                                   const float* __restrict__ w,
                                                   float* __restrict__ hpre) {
    int og = blockIdx.y, b = blockIdx.z;
    int p = blockIdx.x * 256 + threadIdx.x;
    const float* wr = w + (size_t)og * 16 * DM;
    const float* xb = x + (size_t)b * DM * HW + p;
    v2f acc[16];
#pragma unroll
    for (int j = 0; j < 16; ++j) acc[j] = (v2f){0.f, 0.f};
    for (int c = 0; c < DM; c += 4) {
        float x0 = xb[(size_t)(c + 0) * HW];
        float x1 = xb[(size_t)(c + 1) * HW];
        float x2 = xb[(size_t)(c + 2) * HW];
        float x3 = xb[(size_t)(c + 3) * HW];
        v2f xA = {x0, x1}, xB = {x2, x3};
#pragma unroll
        for (int j = 0; j < 16; ++j) {
            const v2f* wv = reinterpret_cast<const v2f*>(wr + j * DM + c);  // uniform
            acc[j] = __builtin_elementwise_fma(wv[0], xA, acc[j]);
            acc[j] = __builtin_elementwise_fma(wv[1], xB, acc[j]);
        }
    }
    float* hb = hpre + (size_t)b * DI * HW + (size_t)(og * 16) * HW + p;
#pragma unroll
    for (int j = 0; j < 16; ++j) {
        float v = acc[j].x + acc[j].y;
        hb[(size_t)j * HW] = v * fastrcp(1.0f + __expf(-v));
    }
}

// ---------------- K2: depthwise 3x3 conv + bias ----------------
// grid (16, 384, 2), block 256.
__global__ __launch_bounds__(256) void k_dwconv(const float* __restrict__ hpre,
                                                const float* __restrict__ w,
                                                const float* __restrict__ bias,
                                                float* __restrict__ h) {
    int c = blockIdx.y, b = blockIdx.z;
    int p = blockIdx.x * 256 + threadIdx.x;
    int i = p >> 6, j = p & 63;
    const float* wp = w + c * 9;
    const float* src = hpre + ((size_t)b * DI + c) * HW;
    float acc = bias[c];
#pragma unroll
    for (int di = -1; di <= 1; ++di) {
        int ii = i + di;
        if (ii < 0 || ii >= HH) continue;
#pragma unroll
        for (int dj = -1; dj <= 1; ++dj) {
            int jj = j + dj;
            if (jj < 0 || jj >= WW) continue;
            acc = fmaf(wp[(di + 1) * 3 + (dj + 1)], src[ii * WW + jj], acc);
        }
    }
    h[((size_t)b * DI + c) * HW + p] = acc;
}

// ---------------- K3: x_down -> xp column-major [b][w][q][h] ----------------
// grid (128), block 256 = 4 waves. Wave = 96-channel slice; 64 pixels/block.
__global__ __launch_bounds__(256) void k_xdown(const float* __restrict__ h,
                                               const float* __restrict__ w,
                                               float* __restrict__ xpt) {
    __shared__ float red[4][64][17];
    int tid = threadIdx.x;
    int px = tid & 63, cw = tid >> 6;
    int gp = blockIdx.x * 64 + px;
    int b = gp >> 12, p = gp & 4095;
    const float* hb = h + (size_t)b * DI * HW + p;
    int c0 = cw * 96;
    v2f a[16];
#pragma unroll
    for (int s = 0; s < 16; ++s) a[s] = (v2f){0.f, 0.f};
    for (int cc = 0; cc < 96; cc += 4) {
        float h0 = hb[(size_t)(c0 + cc + 0) * HW];
        float h1 = hb[(size_t)(c0 + cc + 1) * HW];
        float h2 = hb[(size_t)(c0 + cc + 2) * HW];
        float h3 = hb[(size_t)(c0 + cc + 3) * HW];
        v2f xA = {h0, h1}, xB = {h2, h3};
#pragma unroll
        for (int s = 0; s < 16; ++s) {
            const v2f* wv = reinterpret_cast<const v2f*>(w + (size_t)s * DI + c0 + cc);
            a[s] = __builtin_elementwise_fma(wv[0], xA, a[s]);
            a[s] = __builtin_elementwise_fma(wv[1], xB, a[s]);
        }
    }
#pragma unroll
    for (int s = 0; s < 16; ++s) red[cw][px][s] = a[s].x + a[s].y;
    __syncthreads();
    int sg = tid >> 6;  // state quad
    float4 r;
    float* o = &r.x;
#pragma unroll
    for (int j = 0; j < 4; ++j) {
        int s = sg * 4 + j;
        o[j] = red[0][px][s] + red[1][px][s] + red[2][px][s] + red[3][px][s];
    }
    int hp = p >> 6, wp_ = p & 63;
    reinterpret_cast<float4*>(xpt)[(size_t)b * (HW * 4) + (wp_ * 4 + sg) * 64 + hp] = r;
}

// ---------------- K4: fused gate-recurrent scan, all 4 directions ----------------
// grid (384, 2), block 128 (2 waves). Wave 0 runs directions {0,2}; wave 1
// runs {1,3} as TWO independent recurrence chains packed in v2f lanes:
// the xp quads are shared, the bpermute latencies of the two chains hide
// under each other, and both chains' outputs merge in-register before one
// atomicAdd per column.
__global__ __launch_bounds__(128, 2) void k_scan(const float* __restrict__ h,
                                                 const float* __restrict__ xpt,
                                                 const float* __restrict__ wup,
                                                 const float* __restrict__ lup,
                                                 const float* __restrict__ uup,
                                                 const float* __restrict__ dup,
                                                 const float* __restrict__ mw,
                                                 float* __restrict__ y) {
    int c = blockIdx.x, b = blockIdx.y;
    int tid = threadIdx.x;
    int wid = tid >> 6, hl = tid & 63;
    int dA = wid, dB = wid + 2;

    __shared__ float htile[64][65];
    __shared__ float acc[64][65];

    const float* hb = h + ((size_t)b * DI + c) * HW;
    for (int i = tid; i < HW; i += 128) {
        htile[i >> 6][i & 63] = hb[i];
        acc[i >> 6][i & 63] = 0.f;
    }

    // Weight pairs {dA, dB} packed in v2f; m_w folded into U and D.
    int rowA = dA * DI + c, rowB = dB * DI + c;
    const float* a1 = wup + (size_t)rowA * DS;
    const float* b1 = wup + (size_t)rowB * DS;
    const float* a2 = wup + (size_t)(4 * DI + rowA) * DS;
    const float* b2 = wup + (size_t)(4 * DI + rowB) * DS;
    const float* a3 = wup + (size_t)(8 * DI + rowA) * DS;
    const float* b3 = wup + (size_t)(8 * DI + rowB) * DS;
    const float* aL = lup + (size_t)rowA * DS;
    const float* bL = lup + (size_t)rowB * DS;
    const float* aU = uup + (size_t)rowA * DS;
    const float* bU = uup + (size_t)rowB * DS;
    const float* aD = dup + (size_t)rowA * DS;
    const float* bD = dup + (size_t)rowB * DS;
    float mdA = mw[dA], mdB = mw[dB];
    v2f w1p[16], w2p[16], w3p[16], wLp[16], wUp[16], wDp[16];
#pragma unroll
    for (int s = 0; s < 16; ++s) {
        w1p[s] = (v2f){a1[s], b1[s]};
        w2p[s] = (v2f){a2[s], b2[s]};
        w3p[s] = (v2f){a3[s], b3[s]};
        wLp[s] = (v2f){aL[s], bL[s]};
        wUp[s] = (v2f){mdA * aU[s], mdB * bU[s]};
        wDp[s] = (v2f){mdA * aD[s], mdB * bD[s]};
    }

    // X walks: chain A = dir wid (forward), chain B = dir wid+2 (reversed).
    int stepA = wid ? 65 : 1;
    int baseA = wid ? hl : hl * 65;
    int stepB = -stepA;
    int baseB = baseA + stepA * 63;
    const float* xpa = &htile[0][0] + baseA;
    const float* xpb = &htile[0][0] + baseB;

    int upAd = ((hl - 1) & 63) << 2;
    int dnAd = ((hl + 1) & 63) << 2;
    bool isTop = (hl == 0), isBot = (hl == 63);

    float* accp = &acc[hl][0];

    const float4* xg = reinterpret_cast<const float4*>(xpt) + (size_t)b * (HW * 4) + hl;

    struct SState {
        v2f g1, g2, g3, L, U, Dv;
        float invA, invB, XA, XB;
    };

    float hprevA, hprevB;
    int uprA, dnrA, uprB, dnrB;

    auto prep = [&](const Q4& q0, const Q4& q1, const Q4& q2, const Q4& q3, SState& S) {
        const float xv[16] = {q0.f4.x, q0.f4.y, q0.f4.z, q0.f4.w,
                              q1.f4.x, q1.f4.y, q1.f4.z, q1.f4.w,
                              q2.f4.x, q2.f4.y, q2.f4.z, q2.f4.w,
                              q3.f4.x, q3.f4.y, q3.f4.z, q3.f4.w};
        v2f g1 = {0.f, 0.f}, g2 = {0.f, 0.f}, g3 = {0.f, 0.f};
        v2f L = {0.f, 0.f}, U = {0.f, 0.f}, Dv = {0.f, 0.f};
#pragma unroll
        for (int s = 0; s < 16; ++s) {
            v2f xs = {xv[s], xv[s]};
            g1 = __builtin_elementwise_fma(w1p[s], xs, g1);
            g2 = __builtin_elementwise_fma(w2p[s], xs, g2);
            g3 = __builtin_elementwise_fma(w3p[s], xs, g3);
            L  = __builtin_elementwise_fma(wLp[s], xs, L);
            U  = __builtin_elementwise_fma(wUp[s], xs, U);
            Dv = __builtin_elementwise_fma(wDp[s], xs, Dv);
        }
        S.g1 = (v2f){fsig(g1.x), fsig(g1.y)};
        S.g2 = (v2f){fsig(g2.x), fsig(g2.y)};
        S.g3 = (v2f){fsig(g3.x), fsig(g3.y)};
        S.L = L; S.U = U; S.Dv = Dv;
        float sA = S.g2.x + (isTop ? 0.f : S.g1.x) + (isBot ? 0.f : S.g3.x);
        float sB = S.g2.y + (isTop ? 0.f : S.g1.y) + (isBot ? 0.f : S.g3.y);
        S.invA = fastrcp(fmaxf(sA, 1e-7f));
        S.invB = fastrcp(fmaxf(sB, 1e-7f));
        S.XA = *xpa; xpa += stepA;
        S.XB = *xpb; xpb += stepB;
    };

    auto comb = [&](const SState& S) {
        float upAv = isTop ? 0.f : __int_as_float(uprA);
        float dnAv = isBot ? 0.f : __int_as_float(dnrA);
        float upBv = isTop ? 0.f : __int_as_float(uprB);
        float dnBv = isBot ? 0.f : __int_as_float(dnrB);
        float hnA = fmaf(S.L.x, S.XA,
                         S.invA * fmaf(S.g1.x, upAv, fmaf(S.g2.x, hprevA, S.g3.x * dnAv)));
        float hnB = fmaf(S.L.y, S.XB,
                         S.invB * fmaf(S.g1.y, upBv, fmaf(S.g2.y, hprevB, S.g3.y * dnBv)));
        atomicAdd(accp, fmaf(hnA, S.U.x, S.XA * S.Dv.x) + fmaf(hnB, S.U.y, S.XB * S.Dv.y));
        accp += 1;
        hprevA = hnA; hprevB = hnB;
        uprA = __builtin_amdgcn_ds_bpermute(upAd, __float_as_int(hnA));
        dnrA = __builtin_amdgcn_ds_bpermute(dnAd, __float_as_int(hnA));
        uprB = __builtin_amdgcn_ds_bpermute(upAd, __float_as_int(hnB));
        dnrB = __builtin_amdgcn_ds_bpermute(dnAd, __float_as_int(hnB));
    };

#define LOADQ(R0, R1, R2, R3, wcol) { \
    const float4* pp_ = xg + (size_t)(wcol) * 256; \
    R0.f4 = pp_[0]; R1.f4 = pp_[64]; R2.f4 = pp_[128]; R3.f4 = pp_[192]; }

    Q4 A0, A1, A2, A3, B0, B1, B2, B3;
    SState Sa, Sb;

    LOADQ(A0, A1, A2, A3, 0);
    __syncthreads();  // htile + acc ready (prep reads htile)

    prep(A0, A1, A2, A3, Sa);  // col 0
    LOADQ(A0, A1, A2, A3, 1);
    // col 0: hprev = up = dn = 0 -> hnew = L*X
    hprevA = Sa.L.x * Sa.XA;
    hprevB = Sa.L.y * Sa.XB;
    atomicAdd(accp, fmaf(hprevA, Sa.U.x, Sa.XA * Sa.Dv.x) +
                    fmaf(hprevB, Sa.U.y, Sa.XB * Sa.Dv.y));
    accp += 1;
    uprA = __builtin_amdgcn_ds_bpermute(upAd, __float_as_int(hprevA));
    dnrA = __builtin_amdgcn_ds_bpermute(dnAd, __float_as_int(hprevA));
    uprB = __builtin_amdgcn_ds_bpermute(upAd, __float_as_int(hprevB));
    dnrB = __builtin_amdgcn_ds_bpermute(dnAd, __float_as_int(hprevB));
    LOADQ(B0, B1, B2, B3, 2);

    for (int w = 1; w < 63; w += 2) {
        prep(A0, A1, A2, A3, Sb);   // col w
        LOADQ(A0, A1, A2, A3, w + 2);
        comb(Sb);                    // col w
        prep(B0, B1, B2, B3, Sa);   // col w+1
        int wn = (w + 3 < 64) ? w + 3 : 63;
        LOADQ(B0, B1, B2, B3, wn);
        comb(Sa);                    // col w+1
    }
    // col 63 (A holds it)
    prep(A0, A1, A2, A3, Sb);
    {
        float upAv = isTop ? 0.f : __int_as_float(uprA);
        float dnAv = isBot ? 0.f : __int_as_float(dnrA);
        float upBv = isTop ? 0.f : __int_as_float(uprB);
        float dnBv = isBot ? 0.f : __int_as_float(dnrB);
        float hnA = fmaf(Sb.L.x, Sb.XA,
                         Sb.invA * fmaf(Sb.g1.x, upAv, fmaf(Sb.g2.x, hprevA, Sb.g3.x * dnAv)));
        float hnB = fmaf(Sb.L.y, Sb.XB,
                         Sb.invB * fmaf(Sb.g1.y, upBv, fmaf(Sb.g2.y, hprevB, Sb.g3.y * dnBv)));
        atomicAdd(accp, fmaf(hnA, Sb.U.x, Sb.XA * Sb.Dv.x) +
                        fmaf(hnB, Sb.U.y, Sb.XB * Sb.Dv.y));
    }
#undef LOADQ

    __syncthreads();
    float* yb = y + ((size_t)b * DI + c) * HW;
    for (int i = tid; i < HW; i += 128) yb[i] = acc[i >> 6][i & 63];
}

// ---------------- K5: LayerNorm2d over channels, in-place, single pass ----------------
// grid (512), block 256. Block: 16 pixels x 16 channel-chunks (24 channels each).
__global__ __launch_bounds__(256) void k_ln(float* __restrict__ y,
                                            const float* __restrict__ nw,
                                            const float* __restrict__ nb) {
    int lpx = threadIdx.x & 15, chunk = threadIdx.x >> 4;
    int gp = blockIdx.x * 16 + lpx;  // global pixel 0..8191
    int b = gp >> 12, p = gp & 4095;
    float* yb = y + (size_t)b * DI * HW + p;

    float vv[24];
    float s = 0.f, s2 = 0.f;
#pragma unroll
    for (int ci = 0; ci < 24; ++ci) {
        float v = yb[(size_t)(chunk * 24 + ci) * HW];
        vv[ci] = v;
        s += v;
        s2 = fmaf(v, v, s2);
    }
    __shared__ float S[16][17], S2[16][17];
    S[chunk][lpx] = s;
    S2[chunk][lpx] = s2;
    __syncthreads();
    float ts = 0.f, ts2 = 0.f;
#pragma unroll
    for (int k = 0; k < 16; ++k) { ts += S[k][lpx]; ts2 += S2[k][lpx]; }
    float mu = ts * (1.0f / DI);
    float var = ts2 * (1.0f / DI) - mu * mu;
    float inv = rsqrtf(var + 1e-5f);
#pragma unroll
    for (int ci = 0; ci < 24; ++ci) {
        int cch = chunk * 24 + ci;
        float v = (vv[ci] - mu) * inv;
        yb[(size_t)cch * HW] = fmaf(v, nw[cch], nb[cch]);
    }
}

// ---------------- K6: GRN per-channel sumsq -> Gx = sqrt(sum y^2) ----------------
// grid (384, 2), block 256.
__global__ __launch_bounds__(256) void k_grnsum(const float* __restrict__ y,
                                                float* __restrict__ gx) {
    int c = blockIdx.x, b = blockIdx.y;
    const float* yb = y + ((size_t)b * DI + c) * HW;
    float s = 0.f;
#pragma unroll 4
    for (int i = threadIdx.x; i < HW; i += 256) {
        float v = yb[i];
        s = fmaf(v, v, s);
    }
#pragma unroll
    for (int o = 32; o > 0; o >>= 1) s += __shfl_down(s, o);
    __shared__ float red[4];
    int wid = threadIdx.x >> 6;
    if ((threadIdx.x & 63) == 0) red[wid] = s;
    __syncthreads();
    if (threadIdx.x == 0) gx[b * DI + c] = sqrtf(red[0] + red[1] + red[2] + red[3]);
}

// ---------------- K7: GRN scale: sc = 1 + gamma * Gx/(mean+1e-6) ----------------
// grid 2, block 256. Each thread covers channels cidx and cidx+256 (DI=384).
__global__ __launch_bounds__(256) void k_grnscale(const float* __restrict__ gxv,
                                                  const float* __restrict__ gamma,
                                                  float* __restrict__ sc) {
    int b = blockIdx.x;
    const float* g = gxv + b * DI;
    int cidx = threadIdx.x;
    float gx0 = g[cidx];
    float gx1 = (cidx < DI - 256) ? g[cidx + 256] : 0.f;
    float s = gx0 + gx1;
#pragma unroll
    for (int o = 32; o > 0; o >>= 1) s += __shfl_down(s, o);
    __shared__ float red[4];
    __shared__ float meanv;
    int wid = threadIdx.x >> 6;
    if ((threadIdx.x & 63) == 0) red[wid] = s;
    __syncthreads();
    if (threadIdx.x == 0) meanv = (red[0] + red[1] + red[2] + red[3]) * (1.0f / DI);
    __syncthreads();
    float m = meanv + 1e-6f;
    sc[b * DI + cidx] = 1.0f + gamma[cidx] * (gx0 / m);
    if (cidx < DI - 256)
        sc[b * DI + cidx + 256] = 1.0f + gamma[cidx + 256] * (gx1 / m);
}

// ---------------- K8: out_proj GEMM fused with GRN scale/shift ----------------
// grid (16, 24, 2), block 256. Packed dual-FMA over channel pairs.
__global__ __launch_bounds__(256, 3) void k_outproj(const float* __restrict__ y,
                                                    const float* __restrict__ w,
                                                    const float* __restrict__ sc_all,
                                                    const float* __restrict__ beta,
                                                    float* __restrict__ out) {
    int og = blockIdx.y, b = blockIdx.z;
    int p = blockIdx.x * 256 + threadIdx.x;
    const float* wr = w + (size_t)og * 8 * DI;
    const float* scb = sc_all + b * DI;
    const float* yb = y + (size_t)b * DI * HW + p;
    v2f acc[8];
#pragma unroll
    for (int j = 0; j < 8; ++j) acc[j] = (v2f){0.f, 0.f};
    for (int c = 0; c < DI; c += 4) {
        float v0 = fmaf(yb[(size_t)(c + 0) * HW], scb[c + 0], beta[c + 0]);
        float v1 = fmaf(yb[(size_t)(c + 1) * HW], scb[c + 1], beta[c + 1]);
        float v2 = fmaf(yb[(size_t)(c + 2) * HW], scb[c + 2], beta[c + 2]);
        float v3 = fmaf(yb[(size_t)(c + 3) * HW], scb[c + 3], beta[c + 3]);
        v2f vA = {v0, v1}, vB = {v2, v3};
#pragma unroll
        for (int j = 0; j < 8; ++j) {
            const v2f* wv = reinterpret_cast<const v2f*>(wr + j * DI + c);  // uniform
            acc[j] = __builtin_elementwise_fma(wv[0], vA, acc[j]);
            acc[j] = __builtin_elementwise_fma(wv[1], vB, acc[j]);
        }
    }
    float* ob = out + (size_t)b * DM * HW + (size_t)(og * 8) * HW + p;
#pragma unroll
    for (int j = 0; j < 8; ++j) ob[(size_t)j * HW] = acc[j].x + acc[j].y;
}

extern "C" void kernel_launch(void* const* d_in, const int* in_sizes, int n_in,
                              void* d_out, int out_size, void* d_ws, size_t ws_size,
                              hipStream_t stream) {
    (void)in_sizes; (void)n_in; (void)out_size; (void)ws_size;
    const float* x          = (const float*)d_in[0];
    const float* in_proj_w  = (const float*)d_in[1];
    const float* dwconv_w   = (const float*)d_in[2];
    const float* dwconv_b   = (const float*)d_in[3];
    const float* x_down_w   = (const float*)d_in[4];
    const float* w_up_w     = (const float*)d_in[5];
    const float* l_up_w     = (const float*)d_in[6];
    const float* u_up_w     = (const float*)d_in[7];
    const float* d_up_w     = (const float*)d_in[8];
    const float* m_w        = (const float*)d_in[9];
    const float* grn_gamma  = (const float*)d_in[10];
    const float* grn_beta   = (const float*)d_in[11];
    const float* norm_w     = (const float*)d_in[12];
    const float* norm_b     = (const float*)d_in[13];
    const float* out_proj_w = (const float*)d_in[14];

    float* ws = (float*)d_ws;
    const size_t NBIG = (size_t)Bn * DI * HW;
    float* hpre = ws;                  // [B,DI,H,W], later reused as y
    float* hbuf = ws + NBIG;           // [B,DI,H,W] post-dwconv
    float* xpt  = ws + 2 * NBIG;       // [B,W,4,64] column-major xp
    float* gx   = ws + 2 * NBIG + (size_t)Bn * HW * DS;
    float* sc   = gx + Bn * DI;
    float* y    = hpre;

    k_inproj<<<dim3(16, 24, 2), 256, 0, stream>>>(x, in_proj_w, hpre);
    k_dwconv<<<dim3(16, DI, Bn), 256, 0, stream>>>(hpre, dwconv_w, dwconv_b, hbuf);
    k_xdown<<<dim3(128), 256, 0, stream>>>(hbuf, x_down_w, xpt);
    k_scan<<<dim3(DI, Bn), 128, 0, stream>>>(hbuf, xpt, w_up_w, l_up_w, u_up_w,
                                             d_up_w, m_w, y);
    k_ln<<<dim3(512), 256, 0, stream>>>(y, norm_w, norm_b);
    k_grnsum<<<dim3(DI, Bn), 256, 0, stream>>>(y, gx);
    k_grnscale<<<dim3(Bn), 256, 0, stream>>>(gx, grn_gamma, sc);
    k_outproj<<<dim3(16, 24, 2), 256, 0, stream>>>(y, out_proj_w, sc, grn_beta,
                                                   (float*)d_out);
}

// Round 12
// 228.019 us; speedup vs baseline: 1.1821x; 1.1821x over previous
//
#include <hip/hip_runtime.h>
#include <math.h>

#define Bn 2
#define DM 192
#define DI 384
#define DS 16
#define HH 64
#define WW 64
#define HW 4096
#define ND 4

typedef __attribute__((ext_vector_type(2))) float v2f;

__device__ __forceinline__ float fastrcp(float x) { return __builtin_amdgcn_rcpf(x); }
__device__ __forceinline__ float fsig(float x) {
    return fastrcp(1.0f + __expf(-x));
}

// ---------------- K1: in_proj (1x1) + SiLU ----------------
// grid (16, 24, 2), block 256. Packed v_pk_fma_f32 over channel pairs.
__global__ __launch_bounds__(256, 3) void k_inproj(const float* __restrict__ x,
                                                   const float* __restrict__ w,
                                                   float* __restrict__ hpre) {
    int og = blockIdx.y, b = blockIdx.z;
    int p = blockIdx.x * 256 + threadIdx.x;
    const float* wr = w + (size_t)og * 16 * DM;
    const float* xb = x + (size_t)b * DM * HW + p;
    v2f acc[16];
#pragma unroll
    for (int j = 0; j < 16; ++j) acc[j] = (v2f){0.f, 0.f};
    for (int c = 0; c < DM; c += 4) {
        float x0 = xb[(size_t)(c + 0) * HW];
        float x1 = xb[(size_t)(c + 1) * HW];
        float x2 = xb[(size_t)(c + 2) * HW];
        float x3 = xb[(size_t)(c + 3) * HW];
        v2f xA = {x0, x1}, xB = {x2, x3};
#pragma unroll
        for (int j = 0; j < 16; ++j) {
            const v2f* wv = reinterpret_cast<const v2f*>(wr + j * DM + c);  // uniform
            acc[j] = __builtin_elementwise_fma(wv[0], xA, acc[j]);
            acc[j] = __builtin_elementwise_fma(wv[1], xB, acc[j]);
        }
    }
    float* hb = hpre + (size_t)b * DI * HW + (size_t)(og * 16) * HW + p;
#pragma unroll
    for (int j = 0; j < 16; ++j) {
        float v = acc[j].x + acc[j].y;
        hb[(size_t)j * HW] = v * fastrcp(1.0f + __expf(-v));
    }
}

// ---------------- K2: depthwise 3x3 conv + bias ----------------
// grid (16, 384, 2), block 256.
__global__ __launch_bounds__(256) void k_dwconv(const float* __restrict__ hpre,
                                                const float* __restrict__ w,
                                                const float* __restrict__ bias,
                                                float* __restrict__ h) {
    int c = blockIdx.y, b = blockIdx.z;
    int p = blockIdx.x * 256 + threadIdx.x;
    int i = p >> 6, j = p & 63;
    const float* wp = w + c * 9;
    const float* src = hpre + ((size_t)b * DI + c) * HW;
    float acc = bias[c];
#pragma unroll
    for (int di = -1; di <= 1; ++di) {
        int ii = i + di;
        if (ii < 0 || ii >= HH) continue;
#pragma unroll
        for (int dj = -1; dj <= 1; ++dj) {
            int jj = j + dj;
            if (jj < 0 || jj >= WW) continue;
            acc = fmaf(wp[(di + 1) * 3 + (dj + 1)], src[ii * WW + jj], acc);
        }
    }
    h[((size_t)b * DI + c) * HW + p] = acc;
}

// ---------------- K3: x_down -> xp column-major [b][w][q][h] ----------------
// grid (128), block 256 = 4 waves. Wave = 96-channel slice; 64 pixels/block.
__global__ __launch_bounds__(256) void k_xdown(const float* __restrict__ h,
                                               const float* __restrict__ w,
                                               float* __restrict__ xpt) {
    __shared__ float red[4][64][17];
    int tid = threadIdx.x;
    int px = tid & 63, cw = tid >> 6;
    int gp = blockIdx.x * 64 + px;
    int b = gp >> 12, p = gp & 4095;
    const float* hb = h + (size_t)b * DI * HW + p;
    int c0 = cw * 96;
    v2f a[16];
#pragma unroll
    for (int s = 0; s < 16; ++s) a[s] = (v2f){0.f, 0.f};
    for (int cc = 0; cc < 96; cc += 4) {
        float h0 = hb[(size_t)(c0 + cc + 0) * HW];
        float h1 = hb[(size_t)(c0 + cc + 1) * HW];
        float h2 = hb[(size_t)(c0 + cc + 2) * HW];
        float h3 = hb[(size_t)(c0 + cc + 3) * HW];
        v2f xA = {h0, h1}, xB = {h2, h3};
#pragma unroll
        for (int s = 0; s < 16; ++s) {
            const v2f* wv = reinterpret_cast<const v2f*>(w + (size_t)s * DI + c0 + cc);
            a[s] = __builtin_elementwise_fma(wv[0], xA, a[s]);
            a[s] = __builtin_elementwise_fma(wv[1], xB, a[s]);
        }
    }
#pragma unroll
    for (int s = 0; s < 16; ++s) red[cw][px][s] = a[s].x + a[s].y;
    __syncthreads();
    int sg = tid >> 6;  // state quad
    float4 r;
    float* o = &r.x;
#pragma unroll
    for (int j = 0; j < 4; ++j) {
        int s = sg * 4 + j;
        o[j] = red[0][px][s] + red[1][px][s] + red[2][px][s] + red[3][px][s];
    }
    int hp = p >> 6, wp_ = p & 63;
    reinterpret_cast<float4*>(xpt)[(size_t)b * (HW * 4) + (wp_ * 4 + sg) * 64 + hp] = r;
}

// 16-term dot of VGPR-resident weight array against 4 float4 quads.
#define DOT16(W, q0, q1, q2, q3) \
    fmaf(W[15], q3.w, fmaf(W[14], q3.z, fmaf(W[13], q3.y, fmaf(W[12], q3.x, \
    fmaf(W[11], q2.w, fmaf(W[10], q2.z, fmaf(W[9],  q2.y, fmaf(W[8],  q2.x, \
    fmaf(W[7],  q1.w, fmaf(W[6],  q1.z, fmaf(W[5],  q1.y, fmaf(W[4],  q1.x, \
    fmaf(W[3],  q0.w, fmaf(W[2],  q0.z, fmaf(W[1],  q0.y, W[0] * q0.x)))))))))))))))

// ---------------- K4: fused gate-recurrent scan, all 4 directions ----------------
// grid (384, 2), block 256 (4 waves = 4 directions, lane = h).
// KEY: 96 weight floats don't fit in SGPRs (cap ~102) -> compiler re-issues
// s_loads inside the loop, and SMEM shares the in-order lgkmcnt with DS, so
// every bpermute wait drains to 0 behind ~200cy scalar reloads. Launder the
// (uniform) weights through __shfl(w,0): bpermute results are divergence-
// marked, so they STAY in VGPRs -> zero in-loop s_loads, precise DS waits.
__global__ __launch_bounds__(256, 3) void k_scan(const float* __restrict__ h,
                                                 const float* __restrict__ xpt,
                                                 const float* __restrict__ wup,
                                                 const float* __restrict__ lup,
                                                 const float* __restrict__ uup,
                                                 const float* __restrict__ dup,
                                                 const float* __restrict__ mw,
                                                 float* __restrict__ y) {
    int c = blockIdx.x, b = blockIdx.y;
    int tid = threadIdx.x;
    int d = tid >> 6, hl = tid & 63;

    __shared__ float htile[64][65];
    __shared__ float acc[64][65];

    const float* hb = h + ((size_t)b * DI + c) * HW;
    for (int i = tid; i < HW; i += 256) {
        htile[i >> 6][i & 63] = hb[i];
        acc[i >> 6][i & 63] = 0.f;
    }

    int row = d * DI + c;
    const float* p1 = wup + (size_t)row * DS;
    const float* p2 = wup + (size_t)(4 * DI + row) * DS;
    const float* p3 = wup + (size_t)(8 * DI + row) * DS;
    const float* pL = lup + (size_t)row * DS;
    const float* pU = uup + (size_t)row * DS;
    const float* pD = dup + (size_t)row * DS;
    float md = mw[d];
    float w1[16], w2[16], w3[16], wL[16], wU[16], wD[16];
#pragma unroll
    for (int s = 0; s < 16; ++s) {
        w1[s] = p1[s]; w2[s] = p2[s]; w3[s] = p3[s];
        wL[s] = pL[s]; wU[s] = md * pU[s]; wD[s] = md * pD[s];
    }
    // Launder: values are identical across lanes, but __shfl output is
    // divergence-marked -> kept in VGPRs, not demoted back to SGPRs.
#pragma unroll
    for (int s = 0; s < 16; ++s) {
        w1[s] = __shfl(w1[s], 0);
        w2[s] = __shfl(w2[s], 0);
        w3[s] = __shfl(w3[s], 0);
        wL[s] = __shfl(wL[s], 0);
        wU[s] = __shfl(wU[s], 0);
        wD[s] = __shfl(wD[s], 0);
    }

    int xstep = (d & 1) ? 65 : 1;
    int xbase = (d & 1) ? hl : hl * 65;
    if (d & 2) { xbase += xstep * 63; xstep = -xstep; }
    const float* xptr = &htile[0][0] + xbase;

    int upA = ((hl - 1) & 63) << 2;
    int dnA = ((hl + 1) & 63) << 2;
    bool isTop = (hl == 0), isBot = (hl == 63);

    float* accp = &acc[hl][0];

    const float4* xg = reinterpret_cast<const float4*>(xpt) + (size_t)b * (HW * 4) + hl;

#define LOADQ(R0, R1, R2, R3, wcol) { \
    const float4* pp_ = xg + (size_t)(wcol) * 256; \
    R0 = pp_[0]; R1 = pp_[64]; R2 = pp_[128]; R3 = pp_[192]; }

#define PREP(g1S, g2S, g3S, invS, LS, US, DvS, XS, R0, R1, R2, R3) { \
    g1S = DOT16(w1, R0, R1, R2, R3); \
    g2S = DOT16(w2, R0, R1, R2, R3); \
    g3S = DOT16(w3, R0, R1, R2, R3); \
    LS  = DOT16(wL, R0, R1, R2, R3); \
    US  = DOT16(wU, R0, R1, R2, R3); \
    DvS = DOT16(wD, R0, R1, R2, R3); \
    g1S = fsig(g1S); g2S = fsig(g2S); g3S = fsig(g3S); \
    float ss_ = g2S + (isTop ? 0.f : g1S) + (isBot ? 0.f : g3S); \
    invS = fastrcp(fmaxf(ss_, 1e-7f)); \
    XS = *xptr; xptr += xstep; }

#define COMB(g1S, g2S, g3S, invS, LS, US, DvS, XS) { \
    float upv_ = isTop ? 0.f : __int_as_float(upr); \
    float dnv_ = isBot ? 0.f : __int_as_float(dnr); \
    float hnew_ = fmaf(LS, XS, invS * fmaf(g1S, upv_, fmaf(g2S, hprev, g3S * dnv_))); \
    atomicAdd(accp, fmaf(hnew_, US, XS * DvS)); accp += 1; \
    hprev = hnew_; \
    upr = __builtin_amdgcn_ds_bpermute(upA, __float_as_int(hprev)); \
    dnr = __builtin_amdgcn_ds_bpermute(dnA, __float_as_int(hprev)); }

    float4 A0, A1, A2, A3, B0, B1, B2, B3;
    float g1a, g2a, g3a, inva, La, Ua, Dva, Xa;
    float g1b, g2b, g3b, invb, Lb, Ub, Dvb, Xb;
    int upr, dnr;
    float hprev;

    LOADQ(A0, A1, A2, A3, 0);
    __syncthreads();  // htile + acc ready (PREP reads htile)

    PREP(g1a, g2a, g3a, inva, La, Ua, Dva, Xa, A0, A1, A2, A3);  // col 0
    LOADQ(A0, A1, A2, A3, 1);
    hprev = La * Xa;  // col 0: up = dn = hprev = 0
    atomicAdd(accp, fmaf(hprev, Ua, Xa * Dva)); accp += 1;
    upr = __builtin_amdgcn_ds_bpermute(upA, __float_as_int(hprev));
    dnr = __builtin_amdgcn_ds_bpermute(dnA, __float_as_int(hprev));
    LOADQ(B0, B1, B2, B3, 2);

    for (int w = 1; w < 63; w += 2) {
        PREP(g1b, g2b, g3b, invb, Lb, Ub, Dvb, Xb, A0, A1, A2, A3);  // col w
        LOADQ(A0, A1, A2, A3, w + 2);
        COMB(g1b, g2b, g3b, invb, Lb, Ub, Dvb, Xb);                   // col w
        PREP(g1a, g2a, g3a, inva, La, Ua, Dva, Xa, B0, B1, B2, B3);  // col w+1
        int wn = (w + 3 < 64) ? w + 3 : 63;
        LOADQ(B0, B1, B2, B3, wn);
        COMB(g1a, g2a, g3a, inva, La, Ua, Dva, Xa);                   // col w+1
    }
    // col 63 (A holds it)
    PREP(g1b, g2b, g3b, invb, Lb, Ub, Dvb, Xb, A0, A1, A2, A3);
    {
        float upv_ = isTop ? 0.f : __int_as_float(upr);
        float dnv_ = isBot ? 0.f : __int_as_float(dnr);
        float hnew_ = fmaf(Lb, Xb, invb * fmaf(g1b, upv_, fmaf(g2b, hprev, g3b * dnv_)));
        atomicAdd(accp, fmaf(hnew_, Ub, Xb * Dvb));
    }
#undef LOADQ
#undef PREP
#undef COMB

    __syncthreads();
    float* yb = y + ((size_t)b * DI + c) * HW;
    for (int i = tid; i < HW; i += 256) yb[i] = acc[i >> 6][i & 63];
}

// ---------------- K5: LayerNorm2d over channels, in-place, single pass ----------------
// grid (512), block 256. Block: 16 pixels x 16 channel-chunks (24 channels each).
__global__ __launch_bounds__(256) void k_ln(float* __restrict__ y,
                                            const float* __restrict__ nw,
                                            const float* __restrict__ nb) {
    int lpx = threadIdx.x & 15, chunk = threadIdx.x >> 4;
    int gp = blockIdx.x * 16 + lpx;  // global pixel 0..8191
    int b = gp >> 12, p = gp & 4095;
    float* yb = y + (size_t)b * DI * HW + p;

    float vv[24];
    float s = 0.f, s2 = 0.f;
#pragma unroll
    for (int ci = 0; ci < 24; ++ci) {
        float v = yb[(size_t)(chunk * 24 + ci) * HW];
        vv[ci] = v;
        s += v;
        s2 = fmaf(v, v, s2);
    }
    __shared__ float S[16][17], S2[16][17];
    S[chunk][lpx] = s;
    S2[chunk][lpx] = s2;
    __syncthreads();
    float ts = 0.f, ts2 = 0.f;
#pragma unroll
    for (int k = 0; k < 16; ++k) { ts += S[k][lpx]; ts2 += S2[k][lpx]; }
    float mu = ts * (1.0f / DI);
    float var = ts2 * (1.0f / DI) - mu * mu;
    float inv = rsqrtf(var + 1e-5f);
#pragma unroll
    for (int ci = 0; ci < 24; ++ci) {
        int cch = chunk * 24 + ci;
        float v = (vv[ci] - mu) * inv;
        yb[(size_t)cch * HW] = fmaf(v, nw[cch], nb[cch]);
    }
}

// ---------------- K6: GRN per-channel sumsq -> Gx = sqrt(sum y^2) ----------------
// grid (384, 2), block 256.
__global__ __launch_bounds__(256) void k_grnsum(const float* __restrict__ y,
                                                float* __restrict__ gx) {
    int c = blockIdx.x, b = blockIdx.y;
    const float* yb = y + ((size_t)b * DI + c) * HW;
    float s = 0.f;
#pragma unroll 4
    for (int i = threadIdx.x; i < HW; i += 256) {
        float v = yb[i];
        s = fmaf(v, v, s);
    }
#pragma unroll
    for (int o = 32; o > 0; o >>= 1) s += __shfl_down(s, o);
    __shared__ float red[4];
    int wid = threadIdx.x >> 6;
    if ((threadIdx.x & 63) == 0) red[wid] = s;
    __syncthreads();
    if (threadIdx.x == 0) gx[b * DI + c] = sqrtf(red[0] + red[1] + red[2] + red[3]);
}

// ---------------- K7: weight prep — fold GRN scale into out_proj weights ----------------
// grid (8, 2), block 256. Block: 24 output rows of Wsc[b] = W * sc[b]; block
// recomputes sc from gx (replaces k_grnscale). b==0 blocks also compute
// Wbeta[j] = sum_c W[j,c]*beta[c].
__global__ __launch_bounds__(256) void k_wprep(const float* __restrict__ gxv,
                                               const float* __restrict__ gamma,
                                               const float* __restrict__ w,
                                               const float* __restrict__ beta,
                                               float* __restrict__ wsc,
                                               float* __restrict__ wbeta) {
    int b = blockIdx.y;
    int tid = threadIdx.x;
    const float* g = gxv + b * DI;
    __shared__ float scl[DI];
    __shared__ float red[4];
    __shared__ float meanv;

    float gx0 = g[tid];
    float gx1 = (tid < DI - 256) ? g[tid + 256] : 0.f;
    float s = gx0 + gx1;
#pragma unroll
    for (int o = 32; o > 0; o >>= 1) s += __shfl_down(s, o);
    int wid = tid >> 6;
    if ((tid & 63) == 0) red[wid] = s;
    __syncthreads();
    if (tid == 0) meanv = (red[0] + red[1] + red[2] + red[3]) * (1.0f / DI);
    __syncthreads();
    float m = meanv + 1e-6f;
    scl[tid] = 1.0f + gamma[tid] * (gx0 / m);
    if (tid < DI - 256) scl[tid + 256] = 1.0f + gamma[tid + 256] * (gx1 / m);
    __syncthreads();

    int j0 = blockIdx.x * 24;
    for (int i = tid; i < 24 * DI; i += 256) {
        int j = j0 + (i / DI), cc = i - (i / DI) * DI;
        wsc[((size_t)b * DM + j) * DI + cc] = w[(size_t)j * DI + cc] * scl[cc];
    }
    if (b == 0 && tid < 24) {
        int j = j0 + tid;
        const float* wj = w + (size_t)j * DI;
        float sum = 0.f;
        for (int cc = 0; cc < DI; ++cc) sum = fmaf(wj[cc], beta[cc], sum);
        wbeta[j] = sum;
    }
}

// ---------------- K8: out_proj — pure GEMM with pre-scaled weights ----------------
// grid (16, 24, 2), block 256. Thread: 8 output channels for one pixel.
// out[j,p] = sum_c Wsc[b,j,c]*y[c,p] + Wbeta[j]
__global__ __launch_bounds__(256, 3) void k_outproj(const float* __restrict__ y,
                                                    const float* __restrict__ wsc,
                                                    const float* __restrict__ wbeta,
                                                    float* __restrict__ out) {
    int og = blockIdx.y, b = blockIdx.z;
    int p = blockIdx.x * 256 + threadIdx.x;
    const float* wr = wsc + ((size_t)b * DM + og * 8) * DI;
    const float* yb = y + (size_t)b * DI * HW + p;
    v2f acc[8];
#pragma unroll
    for (int j = 0; j < 8; ++j) acc[j] = (v2f){0.f, 0.f};
    for (int c = 0; c < DI; c += 4) {
        float v0 = yb[(size_t)(c + 0) * HW];
        float v1 = yb[(size_t)(c + 1) * HW];
        float v2 = yb[(size_t)(c + 2) * HW];
        float v3 = yb[(size_t)(c + 3) * HW];
        v2f vA = {v0, v1}, vB = {v2, v3};
#pragma unroll
        for (int j = 0; j < 8; ++j) {
            const v2f* wv = reinterpret_cast<const v2f*>(wr + j * DI + c);  // uniform
            acc[j] = __builtin_elementwise_fma(wv[0], vA, acc[j]);
            acc[j] = __builtin_elementwise_fma(wv[1], vB, acc[j]);
        }
    }
    float* ob = out + (size_t)b * DM * HW + (size_t)(og * 8) * HW + p;
#pragma unroll
    for (int j = 0; j < 8; ++j)
        ob[(size_t)j * HW] = acc[j].x + acc[j].y + wbeta[og * 8 + j];
}

extern "C" void kernel_launch(void* const* d_in, const int* in_sizes, int n_in,
                              void* d_out, int out_size, void* d_ws, size_t ws_size,
                              hipStream_t stream) {
    (void)in_sizes; (void)n_in; (void)out_size; (void)ws_size;
    const float* x          = (const float*)d_in[0];
    const float* in_proj_w  = (const float*)d_in[1];
    const float* dwconv_w   = (const float*)d_in[2];
    const float* dwconv_b   = (const float*)d_in[3];
    const float* x_down_w   = (const float*)d_in[4];
    const float* w_up_w     = (const float*)d_in[5];
    const float* l_up_w     = (const float*)d_in[6];
    const float* u_up_w     = (const float*)d_in[7];
    const float* d_up_w     = (const float*)d_in[8];
    const float* m_w        = (const float*)d_in[9];
    const float* grn_gamma  = (const float*)d_in[10];
    const float* grn_beta   = (const float*)d_in[11];
    const float* norm_w     = (const float*)d_in[12];
    const float* norm_b     = (const float*)d_in[13];
    const float* out_proj_w = (const float*)d_in[14];

    float* ws = (float*)d_ws;
    const size_t NBIG = (size_t)Bn * DI * HW;
    float* hpre  = ws;                   // [B,DI,H,W], later reused as y
    float* hbuf  = ws + NBIG;            // [B,DI,H,W]; dead after k_scan -> Wsc
    float* xpt   = ws + 2 * NBIG;        // [B,W,4,64] column-major xp
    float* gx    = ws + 2 * NBIG + (size_t)Bn * HW * DS;
    float* y     = hpre;
    float* wsc   = hbuf;                 // [B,DM,DI] = 147456 floats
    float* wbeta = hbuf + (size_t)Bn * DM * DI;  // [DM]

    k_inproj<<<dim3(16, 24, 2), 256, 0, stream>>>(x, in_proj_w, hpre);
    k_dwconv<<<dim3(16, DI, Bn), 256, 0, stream>>>(hpre, dwconv_w, dwconv_b, hbuf);
    k_xdown<<<dim3(128), 256, 0, stream>>>(hbuf, x_down_w, xpt);
    k_scan<<<dim3(DI, Bn), 256, 0, stream>>>(hbuf, xpt, w_up_w, l_up_w, u_up_w,
                                             d_up_w, m_w, y);
    k_ln<<<dim3(512), 256, 0, stream>>>(y, norm_w, norm_b);
    k_grnsum<<<dim3(DI, Bn), 256, 0, stream>>>(y, gx);
    k_wprep<<<dim3(8, Bn), 256, 0, stream>>>(gx, grn_gamma, out_proj_w, grn_beta,
                                             wsc, wbeta);
    k_outproj<<<dim3(16, 24, 2), 256, 0, stream>>>(y, wsc, wbeta, (float*)d_out);
}

// Round 16
// 203.282 us; speedup vs baseline: 1.3259x; 1.1217x over previous
//
#include <hip/hip_runtime.h>
#include <math.h>

#define Bn 2
#define DM 192
#define DI 384
#define DS 16
#define HH 64
#define WW 64
#define HW 4096
#define ND 4

__device__ __forceinline__ float fastrcp(float x) { return __builtin_amdgcn_rcpf(x); }
__device__ __forceinline__ float fsig(float x) {
    return fastrcp(1.0f + __expf(-x));
}

// Lane shifts in the VALU pipe (no DS round-trip). row_shr:1 = lane i <-
// lane i-1 within 16-lane rows (rocPRIM DPP-scan semantics); the 3
// row-boundary lanes are patched with readlane + v_writelane_b32.
// MUST be called at full exec (straight-line code): DPP reads of exec=0
// source lanes return bound_ctrl 0 — putting these in a divergent ternary
// was the r13/r15 correctness bug.
#define WLANE(r, s, L) asm("v_writelane_b32 %0, %1, " #L : "+v"(r) : "s"(s))

// up: lane i <- lane i-1 (lane 0 -> 0 via bound_ctrl)
__device__ __forceinline__ float shift_up(float x) {
    int xi = __float_as_int(x);
    int r = __builtin_amdgcn_mov_dpp(xi, 0x111, 0xF, 0xF, true);  // row_shr:1
    int t15 = __builtin_amdgcn_readlane(xi, 15);
    int t31 = __builtin_amdgcn_readlane(xi, 31);
    int t47 = __builtin_amdgcn_readlane(xi, 47);
    WLANE(r, t15, 16);
    WLANE(r, t31, 32);
    WLANE(r, t47, 48);
    return __int_as_float(r);
}
// dn: lane i <- lane i+1 (lane 63 -> 0 via bound_ctrl)
__device__ __forceinline__ float shift_dn(float x) {
    int xi = __float_as_int(x);
    int r = __builtin_amdgcn_mov_dpp(xi, 0x101, 0xF, 0xF, true);  // row_shl:1
    int t16 = __builtin_amdgcn_readlane(xi, 16);
    int t32 = __builtin_amdgcn_readlane(xi, 32);
    int t48 = __builtin_amdgcn_readlane(xi, 48);
    WLANE(r, t16, 15);
    WLANE(r, t32, 31);
    WLANE(r, t48, 47);
    return __int_as_float(r);
}

// ---------------- K1: in_proj (1x1) + SiLU ----------------
// grid (16, 24, 2), block 256.
__global__ __launch_bounds__(256, 3) void k_inproj(const float* __restrict__ x,
                                                   const float* __restrict__ w,
                                                   float* __restrict__ hpre) {
    int og = blockIdx.y, b = blockIdx.z;
    int p = blockIdx.x * 256 + threadIdx.x;
    const float* wr = w + (size_t)og * 16 * DM;
    const float* xb = x + (size_t)b * DM * HW + p;
    float acc[16];
#pragma unroll
    for (int j = 0; j < 16; ++j) acc[j] = 0.f;
    for (int c = 0; c < DM; c += 4) {
        float x0 = xb[(size_t)(c + 0) * HW];
        float x1 = xb[(size_t)(c + 1) * HW];
        float x2 = xb[(size_t)(c + 2) * HW];
        float x3 = xb[(size_t)(c + 3) * HW];
#pragma unroll
        for (int j = 0; j < 16; ++j) {
            const float* wj = wr + j * DM + c;  // wave-uniform -> SGPR
            acc[j] = fmaf(wj[0], x0, fmaf(wj[1], x1, fmaf(wj[2], x2, fmaf(wj[3], x3, acc[j]))));
        }
    }
    float* hb = hpre + (size_t)b * DI * HW + (size_t)(og * 16) * HW + p;
#pragma unroll
    for (int j = 0; j < 16; ++j) {
        float v = acc[j];
        hb[(size_t)j * HW] = v * fastrcp(1.0f + __expf(-v));
    }
}

// ---------------- K2: depthwise 3x3 conv + bias ----------------
// grid (16, 384, 2), block 256.
__global__ __launch_bounds__(256) void k_dwconv(const float* __restrict__ hpre,
                                                const float* __restrict__ w,
                                                const float* __restrict__ bias,
                                                float* __restrict__ h) {
    int c = blockIdx.y, b = blockIdx.z;
    int p = blockIdx.x * 256 + threadIdx.x;
    int i = p >> 6, j = p & 63;
    const float* wp = w + c * 9;
    const float* src = hpre + ((size_t)b * DI + c) * HW;
    float acc = bias[c];
#pragma unroll
    for (int di = -1; di <= 1; ++di) {
        int ii = i + di;
        if (ii < 0 || ii >= HH) continue;
#pragma unroll
        for (int dj = -1; dj <= 1; ++dj) {
            int jj = j + dj;
            if (jj < 0 || jj >= WW) continue;
            acc = fmaf(wp[(di + 1) * 3 + (dj + 1)], src[ii * WW + jj], acc);
        }
    }
    h[((size_t)b * DI + c) * HW + p] = acc;
}

// ---------------- K3: x_down -> xp column-major [b][w][q][h] ----------------
// grid (128), block 256 = 4 waves. Wave = 96-channel slice; 64 pixels/block.
__global__ __launch_bounds__(256) void k_xdown(const float* __restrict__ h,
                                               const float* __restrict__ w,
                                               float* __restrict__ xpt) {
    __shared__ float red[4][64][17];
    int tid = threadIdx.x;
    int px = tid & 63, cw = tid >> 6;
    int gp = blockIdx.x * 64 + px;
    int b = gp >> 12, p = gp & 4095;
    const float* hb = h + (size_t)b * DI * HW + p;
    int c0 = cw * 96;
    float a[16];
#pragma unroll
    for (int s = 0; s < 16; ++s) a[s] = 0.f;
    for (int cc = 0; cc < 96; cc += 4) {
        float h0 = hb[(size_t)(c0 + cc + 0) * HW];
        float h1 = hb[(size_t)(c0 + cc + 1) * HW];
        float h2 = hb[(size_t)(c0 + cc + 2) * HW];
        float h3 = hb[(size_t)(c0 + cc + 3) * HW];
#pragma unroll
        for (int s = 0; s < 16; ++s) {
            const float* ws = w + (size_t)s * DI + c0 + cc;  // wave-uniform -> s_load
            a[s] = fmaf(ws[0], h0, fmaf(ws[1], h1, fmaf(ws[2], h2, fmaf(ws[3], h3, a[s]))));
        }
    }
#pragma unroll
    for (int s = 0; s < 16; ++s) red[cw][px][s] = a[s];
    __syncthreads();
    int sg = tid >> 6;  // state quad
    float4 r;
    float* o = &r.x;
#pragma unroll
    for (int j = 0; j < 4; ++j) {
        int s = sg * 4 + j;
        o[j] = red[0][px][s] + red[1][px][s] + red[2][px][s] + red[3][px][s];
    }
    int hp = p >> 6, wp_ = p & 63;
    // float4 index: b*HW*4 + (w*4 + q)*64 + h
    reinterpret_cast<float4*>(xpt)[(size_t)b * (HW * 4) + (wp_ * 4 + sg) * 64 + hp] = r;
}

// 16-term dot of SGPR-resident weight array against 4 float4 quads.
#define DOT16(W, q0, q1, q2, q3) \
    fmaf(W[15], q3.w, fmaf(W[14], q3.z, fmaf(W[13], q3.y, fmaf(W[12], q3.x, \
    fmaf(W[11], q2.w, fmaf(W[10], q2.z, fmaf(W[9],  q2.y, fmaf(W[8],  q2.x, \
    fmaf(W[7],  q1.w, fmaf(W[6],  q1.z, fmaf(W[5],  q1.y, fmaf(W[4],  q1.x, \
    fmaf(W[3],  q0.w, fmaf(W[2],  q0.z, fmaf(W[1],  q0.y, W[0] * q0.x)))))))))))))))

// ---------------- K4: fused gate-recurrent scan, all 4 directions ----------------
// grid (384, 2), block 256 (4 waves = 4 directions, lane = h).
// Recurrence neighbor exchange via DPP row shifts + readlane/writelane
// boundary patch, executed STRAIGHT-LINE at full exec (no divergent ternary
// around cross-lane ops). Edge lanes 0/63 get 0 from bound_ctrl; 0/1
// multiplicative masks as insurance.
__global__ __launch_bounds__(256, 3) void k_scan(const float* __restrict__ h,
                                                 const float* __restrict__ xpt,
                                                 const float* __restrict__ wup,
                                                 const float* __restrict__ lup,
                                                 const float* __restrict__ uup,
                                                 const float* __restrict__ dup,
                                                 const float* __restrict__ mw,
                                                 float* __restrict__ y) {
    int c = blockIdx.x, b = blockIdx.y;
    int tid = threadIdx.x;
    int d = tid >> 6, hl = tid & 63;

    __shared__ float htile[64][65];
    __shared__ float acc[64][65];

    const float* hb = h + ((size_t)b * DI + c) * HW;
    for (int i = tid; i < HW; i += 256) {
        htile[i >> 6][i & 63] = hb[i];
        acc[i >> 6][i & 63] = 0.f;
    }

    int row = d * DI + c;
    const float* p1 = wup + (size_t)row * DS;
    const float* p2 = wup + (size_t)(4 * DI + row) * DS;
    const float* p3 = wup + (size_t)(8 * DI + row) * DS;
    const float* pL = lup + (size_t)row * DS;
    const float* pU = uup + (size_t)row * DS;
    const float* pD = dup + (size_t)row * DS;
    float md = mw[d];
    float w1[16], w2[16], w3[16], wL[16], wU[16], wD[16];
#pragma unroll
    for (int s = 0; s < 16; ++s) {
        w1[s] = p1[s]; w2[s] = p2[s]; w3[s] = p3[s];
        wL[s] = pL[s]; wU[s] = md * pU[s]; wD[s] = md * pD[s];
    }

    int xstep = (d & 1) ? 65 : 1;
    int xbase = (d & 1) ? hl : hl * 65;
    if (d & 2) { xbase += xstep * 63; xstep = -xstep; }
    const float* xptr = &htile[0][0] + xbase;

    bool isTop = (hl == 0), isBot = (hl == 63);
    float topMul = isTop ? 0.f : 1.f;   // straight-line masks (no branches)
    float botMul = isBot ? 0.f : 1.f;

    float* accp = &acc[hl][0];

    const float4* xg = reinterpret_cast<const float4*>(xpt) + (size_t)b * (HW * 4) + hl;

#define LOADQ(R0, R1, R2, R3, wcol) { \
    const float4* pp_ = xg + (size_t)(wcol) * 256; \
    R0 = pp_[0]; R1 = pp_[64]; R2 = pp_[128]; R3 = pp_[192]; }

#define PREP(g1S, g2S, g3S, invS, LS, US, DvS, XS, R0, R1, R2, R3) { \
    g1S = DOT16(w1, R0, R1, R2, R3); \
    g2S = DOT16(w2, R0, R1, R2, R3); \
    g3S = DOT16(w3, R0, R1, R2, R3); \
    LS  = DOT16(wL, R0, R1, R2, R3); \
    US  = DOT16(wU, R0, R1, R2, R3); \
    DvS = DOT16(wD, R0, R1, R2, R3); \
    g1S = fsig(g1S); g2S = fsig(g2S); g3S = fsig(g3S); \
    float ss_ = fmaf(g1S, topMul, fmaf(g3S, botMul, g2S)); \
    invS = fastrcp(fmaxf(ss_, 1e-7f)); \
    XS = *xptr; xptr += xstep; }

#define COMB(g1S, g2S, g3S, invS, LS, US, DvS, XS) { \
    float upv_ = topMul * shift_up(hprev); \
    float dnv_ = botMul * shift_dn(hprev); \
    float hnew_ = fmaf(LS, XS, invS * fmaf(g1S, upv_, fmaf(g2S, hprev, g3S * dnv_))); \
    atomicAdd(accp, fmaf(hnew_, US, XS * DvS)); accp += 1; \
    hprev = hnew_; }

    float4 A0, A1, A2, A3, B0, B1, B2, B3;
    float g1a, g2a, g3a, inva, La, Ua, Dva, Xa;
    float g1b, g2b, g3b, invb, Lb, Ub, Dvb, Xb;
    float hprev = 0.f;  // col 0: shifts of the zero vector are zero

    LOADQ(A0, A1, A2, A3, 0);
    __syncthreads();  // htile + acc ready (PREP reads htile)
    LOADQ(B0, B1, B2, B3, 1);

    for (int w = 0; w < 64; w += 2) {
        PREP(g1a, g2a, g3a, inva, La, Ua, Dva, Xa, A0, A1, A2, A3);  // col w
        int wn2 = (w + 2 < 64) ? w + 2 : 63;
        LOADQ(A0, A1, A2, A3, wn2);
        COMB(g1a, g2a, g3a, inva, La, Ua, Dva, Xa);                   // col w
        PREP(g1b, g2b, g3b, invb, Lb, Ub, Dvb, Xb, B0, B1, B2, B3);  // col w+1
        int wn3 = (w + 3 < 64) ? w + 3 : 63;
        LOADQ(B0, B1, B2, B3, wn3);
        COMB(g1b, g2b, g3b, invb, Lb, Ub, Dvb, Xb);                   // col w+1
    }
#undef LOADQ
#undef PREP
#undef COMB

    __syncthreads();
    float* yb = y + ((size_t)b * DI + c) * HW;
    for (int i = tid; i < HW; i += 256) yb[i] = acc[i >> 6][i & 63];
}

// ---------------- K5: LayerNorm2d over channels, in-place, single pass ----------------
// grid (512), block 256. Block: 16 pixels x 16 channel-chunks (24 channels each).
__global__ __launch_bounds__(256) void k_ln(float* __restrict__ y,
                                            const float* __restrict__ nw,
                                            const float* __restrict__ nb) {
    int lpx = threadIdx.x & 15, chunk = threadIdx.x >> 4;
    int gp = blockIdx.x * 16 + lpx;  // global pixel 0..8191
    int b = gp >> 12, p = gp & 4095;
    float* yb = y + (size_t)b * DI * HW + p;

    float vv[24];
    float s = 0.f, s2 = 0.f;
#pragma unroll
    for (int ci = 0; ci < 24; ++ci) {
        float v = yb[(size_t)(chunk * 24 + ci) * HW];
        vv[ci] = v;
        s += v;
        s2 = fmaf(v, v, s2);
    }
    __shared__ float S[16][17], S2[16][17];
    S[chunk][lpx] = s;
    S2[chunk][lpx] = s2;
    __syncthreads();
    float ts = 0.f, ts2 = 0.f;
#pragma unroll
    for (int k = 0; k < 16; ++k) { ts += S[k][lpx]; ts2 += S2[k][lpx]; }
    float mu = ts * (1.0f / DI);
    float var = ts2 * (1.0f / DI) - mu * mu;
    float inv = rsqrtf(var + 1e-5f);
#pragma unroll
    for (int ci = 0; ci < 24; ++ci) {
        int cch = chunk * 24 + ci;
        float v = (vv[ci] - mu) * inv;
        yb[(size_t)cch * HW] = fmaf(v, nw[cch], nb[cch]);
    }
}

// ---------------- K6: GRN per-channel sumsq -> Gx = sqrt(sum y^2) ----------------
// grid (384, 2), block 256.
__global__ __launch_bounds__(256) void k_grnsum(const float* __restrict__ y,
                                                float* __restrict__ gx) {
    int c = blockIdx.x, b = blockIdx.y;
    const float* yb = y + ((size_t)b * DI + c) * HW;
    float s = 0.f;
#pragma unroll 4
    for (int i = threadIdx.x; i < HW; i += 256) {
        float v = yb[i];
        s = fmaf(v, v, s);
    }
#pragma unroll
    for (int o = 32; o > 0; o >>= 1) s += __shfl_down(s, o);
    __shared__ float red[4];
    int wid = threadIdx.x >> 6;
    if ((threadIdx.x & 63) == 0) red[wid] = s;
    __syncthreads();
    if (threadIdx.x == 0) gx[b * DI + c] = sqrtf(red[0] + red[1] + red[2] + red[3]);
}

// ---------------- K7: GRN scale: sc = 1 + gamma * Gx/(mean+1e-6) ----------------
// grid 2, block 256. Each thread covers channels cidx and cidx+256 (DI=384).
__global__ __launch_bounds__(256) void k_grnscale(const float* __restrict__ gxv,
                                                  const float* __restrict__ gamma,
                                                  float* __restrict__ sc) {
    int b = blockIdx.x;
    const float* g = gxv + b * DI;
    int cidx = threadIdx.x;
    float gx0 = g[cidx];
    float gx1 = (cidx < DI - 256) ? g[cidx + 256] : 0.f;
    float s = gx0 + gx1;
#pragma unroll
    for (int o = 32; o > 0; o >>= 1) s += __shfl_down(s, o);
    __shared__ float red[4];
    __shared__ float meanv;
    int wid = threadIdx.x >> 6;
    if ((threadIdx.x & 63) == 0) red[wid] = s;
    __syncthreads();
    if (threadIdx.x == 0) meanv = (red[0] + red[1] + red[2] + red[3]) * (1.0f / DI);
    __syncthreads();
    float m = meanv + 1e-6f;
    sc[b * DI + cidx] = 1.0f + gamma[cidx] * (gx0 / m);
    if (cidx < DI - 256)
        sc[b * DI + cidx + 256] = 1.0f + gamma[cidx + 256] * (gx1 / m);
}

// ---------------- K8: out_proj GEMM fused with GRN scale/shift ----------------
// grid (16, 24, 2), block 256. Thread: 8 output channels for one pixel.
__global__ __launch_bounds__(256, 3) void k_outproj(const float* __restrict__ y,
                                                    const float* __restrict__ w,
                                                    const float* __restrict__ sc_all,
                                                    const float* __restrict__ beta,
                                                    float* __restrict__ out) {
    int og = blockIdx.y, b = blockIdx.z;
    int p = blockIdx.x * 256 + threadIdx.x;
    const float* wr = w + (size_t)og * 8 * DI;
    const float* scb = sc_all + b * DI;
    const float* yb = y + (size_t)b * DI * HW + p;
    float acc[8];
#pragma unroll
    for (int j = 0; j < 8; ++j) acc[j] = 0.f;
    for (int c = 0; c < DI; c += 4) {
        float v0 = fmaf(yb[(size_t)(c + 0) * HW], scb[c + 0], beta[c + 0]);
        float v1 = fmaf(yb[(size_t)(c + 1) * HW], scb[c + 1], beta[c + 1]);
        float v2 = fmaf(yb[(size_t)(c + 2) * HW], scb[c + 2], beta[c + 2]);
        float v3 = fmaf(yb[(size_t)(c + 3) * HW], scb[c + 3], beta[c + 3]);
#pragma unroll
        for (int j = 0; j < 8; ++j) {
            const float* wj = wr + j * DI + c;  // wave-uniform -> SGPR
            acc[j] = fmaf(wj[0], v0, fmaf(wj[1], v1, fmaf(wj[2], v2, fmaf(wj[3], v3, acc[j]))));
        }
    }
    float* ob = out + (size_t)b * DM * HW + (size_t)(og * 8) * HW + p;
#pragma unroll
    for (int j = 0; j < 8; ++j) ob[(size_t)j * HW] = acc[j];
}

extern "C" void kernel_launch(void* const* d_in, const int* in_sizes, int n_in,
                              void* d_out, int out_size, void* d_ws, size_t ws_size,
                              hipStream_t stream) {
    (void)in_sizes; (void)n_in; (void)out_size; (void)ws_size;
    const float* x          = (const float*)d_in[0];
    const float* in_proj_w  = (const float*)d_in[1];
    const float* dwconv_w   = (const float*)d_in[2];
    const float* dwconv_b   = (const float*)d_in[3];
    const float* x_down_w   = (const float*)d_in[4];
    const float* w_up_w     = (const float*)d_in[5];
    const float* l_up_w     = (const float*)d_in[6];
    const float* u_up_w     = (const float*)d_in[7];
    const float* d_up_w     = (const float*)d_in[8];
    const float* m_w        = (const float*)d_in[9];
    const float* grn_gamma  = (const float*)d_in[10];
    const float* grn_beta   = (const float*)d_in[11];
    const float* norm_w     = (const float*)d_in[12];
    const float* norm_b     = (const float*)d_in[13];
    const float* out_proj_w = (const float*)d_in[14];

    float* ws = (float*)d_ws;
    const size_t NBIG = (size_t)Bn * DI * HW;
    float* hpre = ws;                  // [B,DI,H,W], later reused as y
    float* hbuf = ws + NBIG;           // [B,DI,H,W] post-dwconv
    float* xpt  = ws + 2 * NBIG;       // [B,W,4,64] column-major xp
    float* gx   = ws + 2 * NBIG + (size_t)Bn * HW * DS;
    float* sc   = gx + Bn * DI;
    float* y    = hpre;

    k_inproj<<<dim3(16, 24, 2), 256, 0, stream>>>(x, in_proj_w, hpre);
    k_dwconv<<<dim3(16, DI, Bn), 256, 0, stream>>>(hpre, dwconv_w, dwconv_b, hbuf);
    k_xdown<<<dim3(128), 256, 0, stream>>>(hbuf, x_down_w, xpt);
    k_scan<<<dim3(DI, Bn), 256, 0, stream>>>(hbuf, xpt, w_up_w, l_up_w, u_up_w,
                                             d_up_w, m_w, y);
    k_ln<<<dim3(512), 256, 0, stream>>>(y, norm_w, norm_b);
    k_grnsum<<<dim3(DI, Bn), 256, 0, stream>>>(y, gx);
    k_grnscale<<<dim3(Bn), 256, 0, stream>>>(gx, grn_gamma, sc);
    k_outproj<<<dim3(16, 24, 2), 256, 0, stream>>>(y, out_proj_w, sc, grn_beta,
                                                   (float*)d_out);
}

// Round 17
// 201.871 us; speedup vs baseline: 1.3352x; 1.0070x over previous
//
#include <hip/hip_runtime.h>
#include <math.h>

#define Bn 2
#define DM 192
#define DI 384
#define DS 16
#define HH 64
#define WW 64
#define HW 4096
#define ND 4

typedef __attribute__((ext_vector_type(2))) float v2f;
union Q4 { float4 f4; v2f v2[2]; };

__device__ __forceinline__ float fastrcp(float x) { return __builtin_amdgcn_rcpf(x); }
__device__ __forceinline__ float fsig(float x) {
    return fastrcp(1.0f + __expf(-x));
}

// Lane shifts in the VALU pipe (no DS round-trip). row_shr:1 = lane i <-
// lane i-1 within 16-lane rows; the 3 row-boundary lanes are patched with
// readlane + v_writelane_b32. MUST be called at full exec (straight-line):
// DPP reads of exec=0 source lanes return bound_ctrl 0 (r13/r15 bug).
#define WLANE(r, s, L) asm("v_writelane_b32 %0, %1, " #L : "+v"(r) : "s"(s))

__device__ __forceinline__ float shift_up(float x) {
    int xi = __float_as_int(x);
    int r = __builtin_amdgcn_mov_dpp(xi, 0x111, 0xF, 0xF, true);  // row_shr:1
    int t15 = __builtin_amdgcn_readlane(xi, 15);
    int t31 = __builtin_amdgcn_readlane(xi, 31);
    int t47 = __builtin_amdgcn_readlane(xi, 47);
    WLANE(r, t15, 16);
    WLANE(r, t31, 32);
    WLANE(r, t47, 48);
    return __int_as_float(r);
}
__device__ __forceinline__ float shift_dn(float x) {
    int xi = __float_as_int(x);
    int r = __builtin_amdgcn_mov_dpp(xi, 0x101, 0xF, 0xF, true);  // row_shl:1
    int t16 = __builtin_amdgcn_readlane(xi, 16);
    int t32 = __builtin_amdgcn_readlane(xi, 32);
    int t48 = __builtin_amdgcn_readlane(xi, 48);
    WLANE(r, t16, 15);
    WLANE(r, t32, 31);
    WLANE(r, t48, 47);
    return __int_as_float(r);
}

// ---------------- K1: in_proj (1x1) + SiLU ----------------
// grid (16, 24, 2), block 256.
__global__ __launch_bounds__(256, 3) void k_inproj(const float* __restrict__ x,
                                                   const float* __restrict__ w,
                                                   float* __restrict__ hpre) {
    int og = blockIdx.y, b = blockIdx.z;
    int p = blockIdx.x * 256 + threadIdx.x;
    const float* wr = w + (size_t)og * 16 * DM;
    const float* xb = x + (size_t)b * DM * HW + p;
    float acc[16];
#pragma unroll
    for (int j = 0; j < 16; ++j) acc[j] = 0.f;
    for (int c = 0; c < DM; c += 4) {
        float x0 = xb[(size_t)(c + 0) * HW];
        float x1 = xb[(size_t)(c + 1) * HW];
        float x2 = xb[(size_t)(c + 2) * HW];
        float x3 = xb[(size_t)(c + 3) * HW];
#pragma unroll
        for (int j = 0; j < 16; ++j) {
            const float* wj = wr + j * DM + c;  // wave-uniform -> SGPR
            acc[j] = fmaf(wj[0], x0, fmaf(wj[1], x1, fmaf(wj[2], x2, fmaf(wj[3], x3, acc[j]))));
        }
    }
    float* hb = hpre + (size_t)b * DI * HW + (size_t)(og * 16) * HW + p;
#pragma unroll
    for (int j = 0; j < 16; ++j) {
        float v = acc[j];
        hb[(size_t)j * HW] = v * fastrcp(1.0f + __expf(-v));
    }
}

// ---------------- K2: depthwise 3x3 conv + bias ----------------
// grid (16, 384, 2), block 256.
__global__ __launch_bounds__(256) void k_dwconv(const float* __restrict__ hpre,
                                                const float* __restrict__ w,
                                                const float* __restrict__ bias,
                                                float* __restrict__ h) {
    int c = blockIdx.y, b = blockIdx.z;
    int p = blockIdx.x * 256 + threadIdx.x;
    int i = p >> 6, j = p & 63;
    const float* wp = w + c * 9;
    const float* src = hpre + ((size_t)b * DI + c) * HW;
    float acc = bias[c];
#pragma unroll
    for (int di = -1; di <= 1; ++di) {
        int ii = i + di;
        if (ii < 0 || ii >= HH) continue;
#pragma unroll
        for (int dj = -1; dj <= 1; ++dj) {
            int jj = j + dj;
            if (jj < 0 || jj >= WW) continue;
            acc = fmaf(wp[(di + 1) * 3 + (dj + 1)], src[ii * WW + jj], acc);
        }
    }
    h[((size_t)b * DI + c) * HW + p] = acc;
}

// ---------------- K3: x_down -> xp column-major [b][w][q][h] ----------------
// grid (128), block 256 = 4 waves. Wave = 96-channel slice; 64 pixels/block.
__global__ __launch_bounds__(256) void k_xdown(const float* __restrict__ h,
                                               const float* __restrict__ w,
                                               float* __restrict__ xpt) {
    __shared__ float red[4][64][17];
    int tid = threadIdx.x;
    int px = tid & 63, cw = tid >> 6;
    int gp = blockIdx.x * 64 + px;
    int b = gp >> 12, p = gp & 4095;
    const float* hb = h + (size_t)b * DI * HW + p;
    int c0 = cw * 96;
    float a[16];
#pragma unroll
    for (int s = 0; s < 16; ++s) a[s] = 0.f;
    for (int cc = 0; cc < 96; cc += 4) {
        float h0 = hb[(size_t)(c0 + cc + 0) * HW];
        float h1 = hb[(size_t)(c0 + cc + 1) * HW];
        float h2 = hb[(size_t)(c0 + cc + 2) * HW];
        float h3 = hb[(size_t)(c0 + cc + 3) * HW];
#pragma unroll
        for (int s = 0; s < 16; ++s) {
            const float* ws = w + (size_t)s * DI + c0 + cc;  // wave-uniform -> s_load
            a[s] = fmaf(ws[0], h0, fmaf(ws[1], h1, fmaf(ws[2], h2, fmaf(ws[3], h3, a[s]))));
        }
    }
#pragma unroll
    for (int s = 0; s < 16; ++s) red[cw][px][s] = a[s];
    __syncthreads();
    int sg = tid >> 6;  // state quad
    float4 r;
    float* o = &r.x;
#pragma unroll
    for (int j = 0; j < 4; ++j) {
        int s = sg * 4 + j;
        o[j] = red[0][px][s] + red[1][px][s] + red[2][px][s] + red[3][px][s];
    }
    int hp = p >> 6, wp_ = p & 63;
    // float4 index: b*HW*4 + (w*4 + q)*64 + h
    reinterpret_cast<float4*>(xpt)[(size_t)b * (HW * 4) + (wp_ * 4 + sg) * 64 + hp] = r;
}

// Packed 16-dot: 8 v_pk_fma_f32 in two chains + horizontal add.
// Weights are wave-uniform (SGPR pairs); VOP3P allows 1 SGPR operand.
__device__ __forceinline__ float dot16p(const v2f* __restrict__ W,
                                        const Q4& a0, const Q4& a1,
                                        const Q4& a2, const Q4& a3) {
    v2f t0 = W[0] * a0.v2[0];
    v2f t1 = W[1] * a0.v2[1];
    t0 = __builtin_elementwise_fma(W[2], a1.v2[0], t0);
    t1 = __builtin_elementwise_fma(W[3], a1.v2[1], t1);
    t0 = __builtin_elementwise_fma(W[4], a2.v2[0], t0);
    t1 = __builtin_elementwise_fma(W[5], a2.v2[1], t1);
    t0 = __builtin_elementwise_fma(W[6], a3.v2[0], t0);
    t1 = __builtin_elementwise_fma(W[7], a3.v2[1], t1);
    v2f t = t0 + t1;
    return t.x + t.y;
}

// ---------------- K4: fused gate-recurrent scan, all 4 directions ----------------
// grid (384, 2), block 256 (4 waves = 4 directions, lane = h).
// DPP lane shifts (VALU pipe) + packed v_pk_fma_f32 gate dots: with the
// DS chain gone (r16), the kernel is VALU-issue-bound, so halving the
// 96 FMA/column issue count should finally pay (r10's null was latency-bound).
__global__ __launch_bounds__(256, 3) void k_scan(const float* __restrict__ h,
                                                 const float* __restrict__ xpt,
                                                 const float* __restrict__ wup,
                                                 const float* __restrict__ lup,
                                                 const float* __restrict__ uup,
                                                 const float* __restrict__ dup,
                                                 const float* __restrict__ mw,
                                                 float* __restrict__ y) {
    int c = blockIdx.x, b = blockIdx.y;
    int tid = threadIdx.x;
    int d = tid >> 6, hl = tid & 63;

    __shared__ float htile[64][65];
    __shared__ float acc[64][65];

    const float* hb = h + ((size_t)b * DI + c) * HW;
    for (int i = tid; i < HW; i += 256) {
        htile[i >> 6][i & 63] = hb[i];
        acc[i >> 6][i & 63] = 0.f;
    }

    int row = d * DI + c;
    const float* p1 = wup + (size_t)row * DS;
    const float* p2 = wup + (size_t)(4 * DI + row) * DS;
    const float* p3 = wup + (size_t)(8 * DI + row) * DS;
    const float* pL = lup + (size_t)row * DS;
    const float* pU = uup + (size_t)row * DS;
    const float* pD = dup + (size_t)row * DS;
    float md = mw[d];
    v2f w1p[8], w2p[8], w3p[8], wLp[8], wUp[8], wDp[8];
#pragma unroll
    for (int k = 0; k < 8; ++k) {
        w1p[k] = *reinterpret_cast<const v2f*>(p1 + 2 * k);
        w2p[k] = *reinterpret_cast<const v2f*>(p2 + 2 * k);
        w3p[k] = *reinterpret_cast<const v2f*>(p3 + 2 * k);
        wLp[k] = *reinterpret_cast<const v2f*>(pL + 2 * k);
        wUp[k] = md * *reinterpret_cast<const v2f*>(pU + 2 * k);
        wDp[k] = md * *reinterpret_cast<const v2f*>(pD + 2 * k);
    }

    int xstep = (d & 1) ? 65 : 1;
    int xbase = (d & 1) ? hl : hl * 65;
    if (d & 2) { xbase += xstep * 63; xstep = -xstep; }
    const float* xptr = &htile[0][0] + xbase;

    bool isTop = (hl == 0), isBot = (hl == 63);
    float topMul = isTop ? 0.f : 1.f;   // straight-line masks (no branches)
    float botMul = isBot ? 0.f : 1.f;

    float* accp = &acc[hl][0];

    const float4* xg = reinterpret_cast<const float4*>(xpt) + (size_t)b * (HW * 4) + hl;

#define LOADQ(R0, R1, R2, R3, wcol) { \
    const float4* pp_ = xg + (size_t)(wcol) * 256; \
    R0.f4 = pp_[0]; R1.f4 = pp_[64]; R2.f4 = pp_[128]; R3.f4 = pp_[192]; }

#define PREP(g1S, g2S, g3S, invS, LS, US, DvS, XS, R0, R1, R2, R3) { \
    g1S = dot16p(w1p, R0, R1, R2, R3); \
    g2S = dot16p(w2p, R0, R1, R2, R3); \
    g3S = dot16p(w3p, R0, R1, R2, R3); \
    LS  = dot16p(wLp, R0, R1, R2, R3); \
    US  = dot16p(wUp, R0, R1, R2, R3); \
    DvS = dot16p(wDp, R0, R1, R2, R3); \
    g1S = fsig(g1S); g2S = fsig(g2S); g3S = fsig(g3S); \
    float ss_ = fmaf(g1S, topMul, fmaf(g3S, botMul, g2S)); \
    invS = fastrcp(fmaxf(ss_, 1e-7f)); \
    XS = *xptr; xptr += xstep; }

#define COMB(g1S, g2S, g3S, invS, LS, US, DvS, XS) { \
    float upv_ = topMul * shift_up(hprev); \
    float dnv_ = botMul * shift_dn(hprev); \
    float hnew_ = fmaf(LS, XS, invS * fmaf(g1S, upv_, fmaf(g2S, hprev, g3S * dnv_))); \
    atomicAdd(accp, fmaf(hnew_, US, XS * DvS)); accp += 1; \
    hprev = hnew_; }

    Q4 A0, A1, A2, A3, B0, B1, B2, B3;
    float g1a, g2a, g3a, inva, La, Ua, Dva, Xa;
    float g1b, g2b, g3b, invb, Lb, Ub, Dvb, Xb;
    float hprev = 0.f;  // col 0: shifts of the zero vector are zero

    LOADQ(A0, A1, A2, A3, 0);
    __syncthreads();  // htile + acc ready (PREP reads htile)
    LOADQ(B0, B1, B2, B3, 1);

    for (int w = 0; w < 64; w += 2) {
        PREP(g1a, g2a, g3a, inva, La, Ua, Dva, Xa, A0, A1, A2, A3);  // col w
        int wn2 = (w + 2 < 64) ? w + 2 : 63;
        LOADQ(A0, A1, A2, A3, wn2);
        COMB(g1a, g2a, g3a, inva, La, Ua, Dva, Xa);                   // col w
        PREP(g1b, g2b, g3b, invb, Lb, Ub, Dvb, Xb, B0, B1, B2, B3);  // col w+1
        int wn3 = (w + 3 < 64) ? w + 3 : 63;
        LOADQ(B0, B1, B2, B3, wn3);
        COMB(g1b, g2b, g3b, invb, Lb, Ub, Dvb, Xb);                   // col w+1
    }
#undef LOADQ
#undef PREP
#undef COMB

    __syncthreads();
    float* yb = y + ((size_t)b * DI + c) * HW;
    for (int i = tid; i < HW; i += 256) yb[i] = acc[i >> 6][i & 63];
}

// ---------------- K5: LayerNorm2d over channels, in-place, single pass ----------------
// grid (512), block 256. Block: 16 pixels x 16 channel-chunks (24 channels each).
__global__ __launch_bounds__(256) void k_ln(float* __restrict__ y,
                                            const float* __restrict__ nw,
                                            const float* __restrict__ nb) {
    int lpx = threadIdx.x & 15, chunk = threadIdx.x >> 4;
    int gp = blockIdx.x * 16 + lpx;  // global pixel 0..8191
    int b = gp >> 12, p = gp & 4095;
    float* yb = y + (size_t)b * DI * HW + p;

    float vv[24];
    float s = 0.f, s2 = 0.f;
#pragma unroll
    for (int ci = 0; ci < 24; ++ci) {
        float v = yb[(size_t)(chunk * 24 + ci) * HW];
        vv[ci] = v;
        s += v;
        s2 = fmaf(v, v, s2);
    }
    __shared__ float S[16][17], S2[16][17];
    S[chunk][lpx] = s;
    S2[chunk][lpx] = s2;
    __syncthreads();
    float ts = 0.f, ts2 = 0.f;
#pragma unroll
    for (int k = 0; k < 16; ++k) { ts += S[k][lpx]; ts2 += S2[k][lpx]; }
    float mu = ts * (1.0f / DI);
    float var = ts2 * (1.0f / DI) - mu * mu;
    float inv = rsqrtf(var + 1e-5f);
#pragma unroll
    for (int ci = 0; ci < 24; ++ci) {
        int cch = chunk * 24 + ci;
        float v = (vv[ci] - mu) * inv;
        yb[(size_t)cch * HW] = fmaf(v, nw[cch], nb[cch]);
    }
}

// ---------------- K6: GRN per-channel sumsq -> Gx = sqrt(sum y^2) ----------------
// grid (384, 2), block 256.
__global__ __launch_bounds__(256) void k_grnsum(const float* __restrict__ y,
                                                float* __restrict__ gx) {
    int c = blockIdx.x, b = blockIdx.y;
    const float* yb = y + ((size_t)b * DI + c) * HW;
    float s = 0.f;
#pragma unroll 4
    for (int i = threadIdx.x; i < HW; i += 256) {
        float v = yb[i];
        s = fmaf(v, v, s);
    }
#pragma unroll
    for (int o = 32; o > 0; o >>= 1) s += __shfl_down(s, o);
    __shared__ float red[4];
    int wid = threadIdx.x >> 6;
    if ((threadIdx.x & 63) == 0) red[wid] = s;
    __syncthreads();
    if (threadIdx.x == 0) gx[b * DI + c] = sqrtf(red[0] + red[1] + red[2] + red[3]);
}

// ---------------- K7: GRN scale: sc = 1 + gamma * Gx/(mean+1e-6) ----------------
// grid 2, block 256. Each thread covers channels cidx and cidx+256 (DI=384).
__global__ __launch_bounds__(256) void k_grnscale(const float* __restrict__ gxv,
                                                  const float* __restrict__ gamma,
                                                  float* __restrict__ sc) {
    int b = blockIdx.x;
    const float* g = gxv + b * DI;
    int cidx = threadIdx.x;
    float gx0 = g[cidx];
    float gx1 = (cidx < DI - 256) ? g[cidx + 256] : 0.f;
    float s = gx0 + gx1;
#pragma unroll
    for (int o = 32; o > 0; o >>= 1) s += __shfl_down(s, o);
    __shared__ float red[4];
    __shared__ float meanv;
    int wid = threadIdx.x >> 6;
    if ((threadIdx.x & 63) == 0) red[wid] = s;
    __syncthreads();
    if (threadIdx.x == 0) meanv = (red[0] + red[1] + red[2] + red[3]) * (1.0f / DI);
    __syncthreads();
    float m = meanv + 1e-6f;
    sc[b * DI + cidx] = 1.0f + gamma[cidx] * (gx0 / m);
    if (cidx < DI - 256)
        sc[b * DI + cidx + 256] = 1.0f + gamma[cidx + 256] * (gx1 / m);
}

// ---------------- K8: out_proj GEMM fused with GRN scale/shift ----------------
// grid (16, 24, 2), block 256. Thread: 8 output channels for one pixel.
__global__ __launch_bounds__(256, 3) void k_outproj(const float* __restrict__ y,
                                                    const float* __restrict__ w,
                                                    const float* __restrict__ sc_all,
                                                    const float* __restrict__ beta,
                                                    float* __restrict__ out) {
    int og = blockIdx.y, b = blockIdx.z;
    int p = blockIdx.x * 256 + threadIdx.x;
    const float* wr = w + (size_t)og * 8 * DI;
    const float* scb = sc_all + b * DI;
    const float* yb = y + (size_t)b * DI * HW + p;
    float acc[8];
#pragma unroll
    for (int j = 0; j < 8; ++j) acc[j] = 0.f;
    for (int c = 0; c < DI; c += 4) {
        float v0 = fmaf(yb[(size_t)(c + 0) * HW], scb[c + 0], beta[c + 0]);
        float v1 = fmaf(yb[(size_t)(c + 1) * HW], scb[c + 1], beta[c + 1]);
        float v2 = fmaf(yb[(size_t)(c + 2) * HW], scb[c + 2], beta[c + 2]);
        float v3 = fmaf(yb[(size_t)(c + 3) * HW], scb[c + 3], beta[c + 3]);
#pragma unroll
        for (int j = 0; j < 8; ++j) {
            const float* wj = wr + j * DI + c;  // wave-uniform -> SGPR
            acc[j] = fmaf(wj[0], v0, fmaf(wj[1], v1, fmaf(wj[2], v2, fmaf(wj[3], v3, acc[j]))));
        }
    }
    float* ob = out + (size_t)b * DM * HW + (size_t)(og * 8) * HW + p;
#pragma unroll
    for (int j = 0; j < 8; ++j) ob[(size_t)j * HW] = acc[j];
}

extern "C" void kernel_launch(void* const* d_in, const int* in_sizes, int n_in,
                              void* d_out, int out_size, void* d_ws, size_t ws_size,
                              hipStream_t stream) {
    (void)in_sizes; (void)n_in; (void)out_size; (void)ws_size;
    const float* x          = (const float*)d_in[0];
    const float* in_proj_w  = (const float*)d_in[1];
    const float* dwconv_w   = (const float*)d_in[2];
    const float* dwconv_b   = (const float*)d_in[3];
    const float* x_down_w   = (const float*)d_in[4];
    const float* w_up_w     = (const float*)d_in[5];
    const float* l_up_w     = (const float*)d_in[6];
    const float* u_up_w     = (const float*)d_in[7];
    const float* d_up_w     = (const float*)d_in[8];
    const float* m_w        = (const float*)d_in[9];
    const float* grn_gamma  = (const float*)d_in[10];
    const float* grn_beta   = (const float*)d_in[11];
    const float* norm_w     = (const float*)d_in[12];
    const float* norm_b     = (const float*)d_in[13];
    const float* out_proj_w = (const float*)d_in[14];

    float* ws = (float*)d_ws;
    const size_t NBIG = (size_t)Bn * DI * HW;
    float* hpre = ws;                  // [B,DI,H,W], later reused as y
    float* hbuf = ws + NBIG;           // [B,DI,H,W] post-dwconv
    float* xpt  = ws + 2 * NBIG;       // [B,W,4,64] column-major xp
    float* gx   = ws + 2 * NBIG + (size_t)Bn * HW * DS;
    float* sc   = gx + Bn * DI;
    float* y    = hpre;

    k_inproj<<<dim3(16, 24, 2), 256, 0, stream>>>(x, in_proj_w, hpre);
    k_dwconv<<<dim3(16, DI, Bn), 256, 0, stream>>>(hpre, dwconv_w, dwconv_b, hbuf);
    k_xdown<<<dim3(128), 256, 0, stream>>>(hbuf, x_down_w, xpt);
    k_scan<<<dim3(DI, Bn), 256, 0, stream>>>(hbuf, xpt, w_up_w, l_up_w, u_up_w,
                                             d_up_w, m_w, y);
    k_ln<<<dim3(512), 256, 0, stream>>>(y, norm_w, norm_b);
    k_grnsum<<<dim3(DI, Bn), 256, 0, stream>>>(y, gx);
    k_grnscale<<<dim3(Bn), 256, 0, stream>>>(gx, grn_gamma, sc);
    k_outproj<<<dim3(16, 24, 2), 256, 0, stream>>>(y, out_proj_w, sc, grn_beta,
                                                   (float*)d_out);
}